// Round 11
// baseline (155.487 us; speedup 1.0000x reference)
//
#include <hip/hip_runtime.h>
#include <math.h>

#define BB   8
#define HH   384
#define WW   384
#define NN   96
#define HWSZ (HH * WW)
#define NSEG (NN - 1)
#define SEGF 12
#define SEGPAD 1152                  // NSEG*SEGF = 1140, padded
#define DMAXV 15.0f
#define ROWS_PER_BLK 12
#define NCHUNK (HH / ROWS_PER_BLK)   // 32
#define CROWS 12
#define CBANDS (HH / CROWS)          // 32
#define MAGICU 0x9E3779B9u
#define W0 40                        // LDS window width (float2 per row)

typedef unsigned long long u64;
typedef unsigned int u32;

// Relaxed agent-scope atomic store of a float pair (8B). Tiny segs handoff only.
__device__ inline void st_pair(float* p, float lo, float hi)
{
    u64 v = ((u64)__float_as_uint(hi) << 32) | (u64)__float_as_uint(lo);
    __hip_atomic_store((u64*)p, v, __ATOMIC_RELAXED, __HIP_MEMORY_SCOPE_AGENT);
}

__device__ inline float ld_f32_coh(const float* p)
{
    u32 v = __hip_atomic_load((u32*)p, __ATOMIC_RELAXED, __HIP_MEMORY_SCOPE_AGENT);
    return __uint_as_float(v);
}

#define WAIT_ALL() asm volatile("s_waitcnt vmcnt(0) lgkmcnt(0)" ::: "memory")

// raw barrier with LDS-only drain: global loads stay in flight across it
__device__ inline void lds_barrier()
{
    asm volatile("s_waitcnt lgkmcnt(0)" ::: "memory");
    __builtin_amdgcn_sched_barrier(0);
    __builtin_amdgcn_s_barrier();
    __builtin_amdgcn_sched_barrier(0);
}

// ---------------------------------------------------------------------------
// Separable 7x7 tap recovery (exact).
// ---------------------------------------------------------------------------
__device__ inline void load_taps(const float* __restrict__ fltr,
                                 float* __restrict__ sg, float* __restrict__ sdg)
{
    int tid = threadIdx.x;
    if (tid < 7) {
        float s = 0.f;
#pragma unroll
        for (int i = 0; i < 7; ++i) s += fabsf(fltr[i * 7 + tid]);
        sg[tid] = s;
    } else if (tid < 14) {
        int r = tid - 7;
        float s = 0.f;
#pragma unroll
        for (int j = 0; j < 7; ++j) s += fltr[r * 7 + j];
        sdg[r] = s;
    }
    __syncthreads();
}

// ---------------------------------------------------------------------------
// Kernel 1: fused separable conv (normal write-back stores; dispatch boundary
// provides coherence to kernel 2).
// ---------------------------------------------------------------------------
__global__ __launch_bounds__(384) void conv_fused(
    const float* __restrict__ pred, const float* __restrict__ fltr,
    float2* __restrict__ g2, float2* __restrict__ gw2)
{
    __shared__ float sg[7], sdg[7];
    load_taps(fltr, sg, sdg);

    int blk = blockIdx.x;            // 256 blocks
    int b = blk & 7;                 // XCD co-location swizzle (perf only)
    int band = blk >> 3;
    int y0 = band * CROWS;
    int x = threadIdx.x;             // column 0..383
    const float* pb = pred + (size_t)b * HWSZ;
    bool xin = (x >= 3) && (x < WW - 3);

    float hg[7], hd[7], hga[7], hda[7];

#pragma unroll
    for (int q = 0; q < CROWS + 6; ++q) {
        float vg = 0.f, vd = 0.f, vga = 0.f, vda = 0.f;
        int r = y0 + q - 3;
        if (r >= 0 && r < HH) {
            const float* row = pb + r * WW;
            if (xin) {
#pragma unroll
                for (int k = 0; k < 7; ++k) {
                    float v  = row[x + k - 3];
                    float av = fabsf(v);
                    vg  = fmaf(v,  sg[k],  vg);
                    vd  = fmaf(v,  sdg[k], vd);
                    vga = fmaf(av, sg[k],  vga);
                    vda = fmaf(av, sdg[k], vda);
                }
            } else {
#pragma unroll
                for (int k = 0; k < 7; ++k) {
                    int ix = x + k - 3;
                    float v  = (ix >= 0 && ix < WW) ? row[ix] : 0.f;
                    float av = fabsf(v);
                    vg  = fmaf(v,  sg[k],  vg);
                    vd  = fmaf(v,  sdg[k], vd);
                    vga = fmaf(av, sg[k],  vga);
                    vda = fmaf(av, sdg[k], vda);
                }
            }
        }
        hg[q % 7] = vg; hd[q % 7] = vd; hga[q % 7] = vga; hda[q % 7] = vda;

        if (q >= 6) {
            int y = y0 + q - 6;
            float o0 = 0.f, o1 = 0.f, o2 = 0.f, o3 = 0.f;
#pragma unroll
            for (int j = 0; j < 7; ++j) {
                int s = (q - 6 + j) % 7;
                o0 = fmaf(hg[s],  sdg[j], o0);
                o1 = fmaf(hd[s],  sg[j],  o1);
                o2 = fmaf(hga[s], sdg[j], o2);
                o3 = fmaf(hda[s], sg[j],  o3);
            }
            size_t gi = (size_t)b * HWSZ + (size_t)y * WW + x;
            g2[gi]  = make_float2(o0 * 10.f, o1 * 10.f);
            gw2[gi] = make_float2(o2 * 10.f, o3 * 10.f);
        }
    }
}

// write-through (coherent) seg record: 6 u64 relaxed atomic stores
__device__ inline void write_seg_wt(float* __restrict__ r,
                                    float py, float px, float qy, float qx, float wseg)
{
    float aby = qy - py, abx = qx - px;
    float denom = aby * aby + abx * abx + 1e-8f;
    float aab = py * aby + px * abx;
    float aa  = py * py + px * px;
    float reach = DMAXV + wseg;
    st_pair(r + 0,  py,  px);
    st_pair(r + 2,  aby, abx);
    st_pair(r + 4,  aab, denom);
    st_pair(r + 6,  1.0f / denom, aa);
    st_pair(r + 8,  wseg, fminf(py, qy) - reach);
    st_pair(r + 10, fmaxf(py, qy) + reach, 0.f);
}

// ---------------------------------------------------------------------------
// Kernel 2: MERGED snake + render with an LDS CONTOUR-BAND WINDOW:
//  - snake blocks stage a per-row window of g2 (384 rows x 40 float2 = 120KB,
//    centered on the initial contour x(y)) into LDS once; position-loop
//    gathers hit LDS (bit-identical copy). Out-of-window lanes fall back to
//    the round-6 pipelined global gather. After the position loop the SAME
//    LDS is restaged with gw2 for the width loop.
//  - render blocks spin on segflag[b] then render; ss aliases the window
//    buffer (window is dead before ss is touched).
//  - ~125 KB LDS -> 1 block/CU; grid is 256 blocks/256 CUs; snake blocks
//    0..7 dispatch first and never wait on render -> deadlock-free.
// All FP expression shapes identical to the verified kernel (absmax 0.0).
// ---------------------------------------------------------------------------
__global__ __launch_bounds__(384) void snake_render(
    const float* __restrict__ pred, const float* __restrict__ nodes,
    const float* __restrict__ widths,
    const float* __restrict__ g2f, const float* __restrict__ gw2f,
    float* __restrict__ segs, u64* __restrict__ pflag,
    u32* __restrict__ segflag, float* __restrict__ out)
{
    __shared__ float2 LW[HH * W0];   // 120 KB contour-band window
    __shared__ float2 posb[2][NN];
    __shared__ float  wbuf[NN];
    __shared__ short  cxw[HH];       // per-row window start (perf-only)
    __shared__ int slo, shi;
    __shared__ float swsum[6];
    float* ss = (float*)LW;          // render staging aliases the window

    int blk = blockIdx.x;            // 256 blocks
    int b   = blk & 7;               // image (XCD co-location, perf-only)
    int band = blk >> 3;             // render chunk
    int t = threadIdx.x;

    int y0r = band * ROWS_PER_BLK;
    const float* pb = pred + (size_t)b * HWSZ + (size_t)y0r * WW + t;
    float pv[ROWS_PER_BLK];
#pragma unroll
    for (int ry = 0; ry < ROWS_PER_BLK; ++ry) pv[ry] = pb[ry * WW];

    if (t == 0) { slo = NSEG; shi = -1; }

    // ================= phase B: snake (blocks 0..7) =================
    if (blk < 8) {
        const float2* gb  = (const float2*)g2f  + (size_t)b * HWSZ;
        const float2* gwb = (const float2*)gw2f + (size_t)b * HWSZ;
        int wv = t >> 6, ln = t & 63;
        int n  = wv * 48 + ln;            // node index (balanced 48/48)
        bool act = (wv < 2) && (ln < 48);
        bool n0f = (n == 0), nlf = (n == NN - 1);

        float py = 0.f, px = 0.f;
        float4 r0 = make_float4(0.f, 0.f, 0.f, 0.f), r1 = r0;
        float wy = 0.f, wx = 0.f;
        bool pxe = false, inw = false;
        int py0i = 0, py1i = 0, pl0 = 0, pl1 = 0;

        // prologue: load node, publish to LDS, issue gather for initial pos
        if (act) {
            float2 p0 = *(const float2*)(nodes + (size_t)(b * NN + n) * 2);
            py = p0.x; px = p0.y;
            posb[0][n] = p0;
            float yc = fminf(fmaxf(py, 0.0f), (float)(HH - 1));
            float xc = fminf(fmaxf(px, 0.0f), (float)(WW - 1));
            int y0i = (int)floorf(yc);
            int x0i = (int)floorf(xc);
            int y1i = min(y0i + 1, HH - 1);
            pxe = (x0i + 1 > WW - 1);
            wy = yc - (float)y0i;
            wx = xc - (float)x0i;
            r0 = *(const float4*)(gb + y0i * WW + x0i);
            r1 = *(const float4*)(gb + y1i * WW + x0i);
        }
        lds_barrier();                    // posb[0] visible to all waves

        // ---- per-row window centers from initial contour (perf-only) ----
        if (t < HH) {
            float yy = (float)t;
            float2 p0 = posb[0][0], plast = posb[0][NN - 1];
            float xi;
            if (yy <= p0.x) xi = p0.y;
            else if (yy >= plast.x) xi = plast.y;
            else {
                int i = 0;
                for (int k = 0; k < NN - 1; ++k)
                    if (posb[0][k].x <= yy) i = k;
                float2 a = posb[0][i], c = posb[0][i + 1];
                xi = a.y + (c.y - a.y) * ((yy - a.x) / fmaxf(c.x - a.x, 1e-6f));
            }
            int cx = (int)xi - W0 / 2;
            cxw[t] = (short)max(0, min(cx, WW - W0));
        }
        __syncthreads();

        // ---- stage g2 window (all 6 waves; ~120 KB from L2/L3) ----
        for (int idx = t; idx < HH * W0; idx += 384) {
            int y = idx / W0;
            int c = idx - y * W0;
            LW[idx] = gb[y * WW + (int)cxw[y] + c];
        }
        __syncthreads();

        // window-aware bilinear (identical math; LDS is a bit-exact copy)
        auto bilinW = [&](const float2* __restrict__ img, float qy, float qx) -> float2 {
            float y = fminf(fmaxf(qy, 0.0f), (float)(HH - 1));
            float x = fminf(fmaxf(qx, 0.0f), (float)(WW - 1));
            int y0i = (int)floorf(y);
            int x0i = (int)floorf(x);
            int y1i = min(y0i + 1, HH - 1);
            bool xe = (x0i + 1 > WW - 1);
            float fy = y - (float)y0i;
            float fx = x - (float)x0i;
            int l0 = x0i - (int)cxw[y0i];
            int l1 = x0i - (int)cxw[y1i];
            int lim = xe ? (W0 - 1) : (W0 - 2);
            float2 v00, v01, v10, v11;
            if (l0 >= 0 && l0 <= lim && l1 >= 0 && l1 <= lim) {
                v00 = LW[y0i * W0 + l0];
                v01 = xe ? v00 : LW[y0i * W0 + l0 + 1];
                v10 = LW[y1i * W0 + l1];
                v11 = xe ? v10 : LW[y1i * W0 + l1 + 1];
            } else {
                float4 q0 = *(const float4*)(img + y0i * WW + x0i);
                float4 q1 = *(const float4*)(img + y1i * WW + x0i);
                v00 = make_float2(q0.x, q0.y);
                v01 = xe ? v00 : make_float2(q0.z, q0.w);
                v10 = make_float2(q1.x, q1.y);
                v11 = xe ? v10 : make_float2(q1.z, q1.w);
            }
            float w00 = (1.f - fy) * (1.f - fx);
            float w01 = (1.f - fy) * fx;
            float w10 = fy * (1.f - fx);
            float w11 = fy * fx;
            return make_float2(v00.x * w00 + v01.x * w01 + v10.x * w10 + v11.x * w11,
                               v00.y * w00 + v01.y * w01 + v10.y * w10 + v11.y * w11);
        };

        // ---- 50 position steps: LDS window + pipelined global fallback ----
        for (int s = 0; s < 50; ++s) {
            const float2* pcur = posb[s & 1];
            float2* pnxt = posb[(s & 1) ^ 1];
            if (act) {
                float2 xm1 = pcur[max(n - 1, 0)];
                float2 xp1 = pcur[min(n + 1, NN - 1)];
                float2 xm2 = pcur[max(n - 2, 0)];
                float2 xp2 = pcur[min(n + 2, NN - 1)];

                float d2m_y = xm2.x - 2.f * xm1.x + py;
                float d2c_y = xm1.x - 2.f * py + xp1.x;
                float d2p_y = py - 2.f * xp1.x + xp2.x;
                float d2m_x = xm2.y - 2.f * xm1.y + px;
                float d2c_x = xm1.y - 2.f * px + xp1.y;
                float d2p_x = px - 2.f * xp1.y + xp2.y;
                d2m_y = n0f ? d2c_y : d2m_y;
                d2m_x = n0f ? d2c_x : d2m_x;
                d2p_y = nlf ? d2c_y : d2p_y;
                d2p_x = nlf ? d2c_x : d2p_x;
                float d4_y = d2m_y - 2.f * d2c_y + d2p_y;
                float d4_x = d2m_x - 2.f * d2c_x + d2p_x;

                // consume gather: LDS window (common) or pipelined global
                float2 v00, v01, v10, v11;
                if (inw) {
                    v00 = LW[py0i * W0 + pl0];
                    v01 = pxe ? v00 : LW[py0i * W0 + pl0 + 1];
                    v10 = LW[py1i * W0 + pl1];
                    v11 = pxe ? v10 : LW[py1i * W0 + pl1 + 1];
                } else {
                    v00 = make_float2(r0.x, r0.y);
                    v01 = pxe ? v00 : make_float2(r0.z, r0.w);
                    v10 = make_float2(r1.x, r1.y);
                    v11 = pxe ? v10 : make_float2(r1.z, r1.w);
                }
                float w00 = (1.f - wy) * (1.f - wx);
                float w01 = (1.f - wy) * wx;
                float w10 = wy * (1.f - wx);
                float w11 = wy * wx;
                float fy = v00.x * w00 + v01.x * w01 + v10.x * w10 + v11.x * w11;
                float fx = v00.y * w00 + v01.y * w01 + v10.y * w10 + v11.y * w11;

                py += 0.1f * (0.01f * d2c_y - 0.01f * d4_y + fy);
                px += 0.1f * (0.01f * d2c_x - 0.01f * d4_x + fx);

                // next step's cell; issue global gather ONLY if out-of-window
                float yc = fminf(fmaxf(py, 0.0f), (float)(HH - 1));
                float xc = fminf(fmaxf(px, 0.0f), (float)(WW - 1));
                int y0i = (int)floorf(yc);
                int x0i = (int)floorf(xc);
                int y1i = min(y0i + 1, HH - 1);
                bool xe = (x0i + 1 > WW - 1);
                wy = yc - (float)y0i;
                wx = xc - (float)x0i;
                int l0 = x0i - (int)cxw[y0i];
                int l1 = x0i - (int)cxw[y1i];
                int lim = xe ? (W0 - 1) : (W0 - 2);
                bool nin = (l0 >= 0) && (l0 <= lim) && (l1 >= 0) && (l1 <= lim);
                if (!nin) {
                    r0 = *(const float4*)(gb + y0i * WW + x0i);
                    r1 = *(const float4*)(gb + y1i * WW + x0i);
                }
                inw = nin; pxe = xe;
                py0i = y0i; py1i = y1i; pl0 = l0; pl1 = l1;

                pnxt[n] = make_float2(py, px);
            }
            lds_barrier();             // LDS drain only; fallbacks stay in flight
        }
        // final positions: posb[0][*] and (py,px) registers

        // ---- restage window with gw2 for the width loop ----
        __syncthreads();               // everyone done reading g2 window
        for (int idx = t; idx < HH * W0; idx += 384) {
            int y = idx / W0;
            int c = idx - y * W0;
            LW[idx] = gwb[y * WW + (int)cxw[y] + c];
        }
        __syncthreads();

        // ---- tangent / normal / width loop (window-aware probes) ----
        float ny_ = 0.f, nx_ = 0.f, wn = 0.f;
        if (act) {
            float2 xm1 = posb[0][max(n - 1, 0)];
            float2 xp1 = posb[0][min(n + 1, NN - 1)];
            float ty, tx;
            if (n0f)      { ty = xp1.x - py;  tx = xp1.y - px; }
            else if (nlf) { ty = py - xm1.x;  tx = px - xm1.y; }
            else          { ty = 0.5f * (xp1.x - xm1.x); tx = 0.5f * (xp1.y - xm1.y); }

            float nn0 = -tx, nn1 = ty;
            float nrm = sqrtf(nn0 * nn0 + nn1 * nn1) + 1e-6f;
            ny_ = nn0 / nrm; nx_ = nn1 / nrm;

            wn = widths[b * NN + n];
            for (int s = 0; s < 10; ++s) {
                float2 gp = bilinW(gwb, py + wn * ny_, px + wn * nx_);
                float2 gm = bilinW(gwb, py - wn * ny_, px - wn * nx_);
                float fw = 0.5f * ((gp.x * ny_ + gp.y * nx_) - (gm.x * ny_ + gm.y * nx_));
                wn = fmaxf(wn + 0.1f * fw, 0.5f);
            }
            wbuf[n] = wn;
        }
        __syncthreads();               // wbuf ready

        // ---- seg write: tiny write-through handoff ----
        if (act && n < NSEG) {
            float2 q = posb[0][n + 1];
            float wq = wbuf[n + 1];
            write_seg_wt(segs + (size_t)b * SEGPAD + (size_t)n * SEGF,
                         py, px, q.x, q.y, 0.5f * (wn + wq));
        }
        WAIT_ALL();                    // this wave's seg stores committed
        __syncthreads();               // all waves committed
        if (t == 0)
            __hip_atomic_store(&segflag[b], MAGICU,
                               __ATOMIC_RELAXED, __HIP_MEMORY_SCOPE_AGENT);
    } else {
        if (t == 0) {
            while (__hip_atomic_load(&segflag[b],
                                     __ATOMIC_RELAXED, __HIP_MEMORY_SCOPE_AGENT) != MAGICU)
                __builtin_amdgcn_s_sleep(8);
            asm volatile("" ::: "memory");
        }
    }

    __syncthreads();                 // segs ready; slo/shi initialized

    // ================= phase C: render 12 rows + partial sum =================
    {
        int y0 = y0r;
        const float* sb = segs + (size_t)b * SEGPAD;
        for (int j = t; j < NSEG * SEGF; j += 384)
            ss[j] = ld_f32_coh(sb + j);      // one-shot coherent staging
        __syncthreads();

        float cy0 = (float)y0, cy1 = (float)(y0 + ROWS_PER_BLK - 1);
        if (t < NSEG) {
            float ylo = ss[t * SEGF + 9];
            float yhi = ss[t * SEGF + 10];
            if (yhi >= cy0 && ylo <= cy1) {
                atomicMin(&slo, t);
                atomicMax(&shi, t);
            }
        }
        __syncthreads();
        int lo = slo, hi = shi;

        float px = (float)t;
        float px2 = px * px;
        float minv[ROWS_PER_BLK];
#pragma unroll
        for (int r = 0; r < ROWS_PER_BLK; ++r) minv[r] = DMAXV;

        for (int si = lo; si <= hi; ++si) {
            const float* r = ss + si * SEGF;
            float ax = r[1], abx = r[3], ws = r[8];
            float bxe = ax + abx;
            float reach = DMAXV + ws + 0.01f;
            if (px < fminf(ax, bxe) - reach || px > fmaxf(ax, bxe) + reach) continue;

            float ay = r[0], aby = r[2];
            float aab = r[4], denom = r[5], invd = r[6], aa = r[7];
            float dotpa_b = fmaf(px, abx, -aab);
            float pa2_b   = fmaf(px, -2.0f * ax, px2 + aa);
#pragma unroll
            for (int ry = 0; ry < ROWS_PER_BLK; ++ry) {
                float py = (float)(y0 + ry);
                float dotpa = fmaf(py, aby, dotpa_b);
                float tt = fminf(fmaxf(dotpa * invd, 0.0f), 1.0f);
                float pa2 = fmaf(py, fmaf(py, 1.0f, -2.0f * ay), pa2_b);
                float d2 = fmaf(tt, fmaf(tt, denom, -2.0f * dotpa), pa2);
                float d = sqrtf(fmaxf(d2, 0.0f));
                float v = fmaxf(d - ws, 0.0f);
                minv[ry] = fminf(minv[ry], v);
            }
        }

        float sq = 0.f;
#pragma unroll
        for (int ry = 0; ry < ROWS_PER_BLK; ++ry) {
            float diff = pv[ry] - minv[ry];
            sq = fmaf(diff, diff, sq);
        }

#pragma unroll
        for (int off = 32; off > 0; off >>= 1) sq += __shfl_down(sq, off, 64);
        if ((t & 63) == 0) swsum[t >> 6] = sq;
        __syncthreads();
        if (t == 0) {
            float tot = swsum[0] + swsum[1] + swsum[2] + swsum[3] + swsum[4] + swsum[5];
            u64 pvv = ((u64)MAGICU << 32) | (u64)__float_as_uint(tot);
            __hip_atomic_store(&pflag[blk], pvv,
                               __ATOMIC_RELAXED, __HIP_MEMORY_SCOPE_AGENT);
        }
    }

    // ================= final reduce: designated block 8 =================
    if (blk == 8) {
        __syncthreads();             // protect swsum reuse
        float v = 0.f;
        if (t < 256) {
            u64 pvv = __hip_atomic_load(&pflag[t], __ATOMIC_RELAXED,
                                        __HIP_MEMORY_SCOPE_AGENT);
            while ((u32)(pvv >> 32) != MAGICU) {
                __builtin_amdgcn_s_sleep(4);
                pvv = __hip_atomic_load(&pflag[t], __ATOMIC_RELAXED,
                                        __HIP_MEMORY_SCOPE_AGENT);
            }
            v = __uint_as_float((u32)pvv);
        }
#pragma unroll
        for (int off = 32; off > 0; off >>= 1) v += __shfl_down(v, off, 64);
        if ((t & 63) == 0) swsum[t >> 6] = v;
        __syncthreads();
        if (t == 0) {
            float tot = swsum[0] + swsum[1] + swsum[2] + swsum[3] + swsum[4] + swsum[5];
            out[0] = tot * (1.0f / (float)(BB * HWSZ));
        }
    }
}

extern "C" void kernel_launch(void* const* d_in, const int* in_sizes, int n_in,
                              void* d_out, int out_size, void* d_ws, size_t ws_size,
                              hipStream_t stream)
{
    const float* pred   = (const float*)d_in[0];   // (8,1,384,384)
    const float* nodes  = (const float*)d_in[1];   // (8,96,2)
    const float* widths = (const float*)d_in[2];   // (8,96)
    const float* fltr   = (const float*)d_in[3];   // (2,1,7,7)
    float* out = (float*)d_out;

    float* ws   = (float*)d_ws;
    float* g2   = ws;                               // 2*B*HW floats (float2 lanes)
    float* gw2  = g2 + (size_t)2 * BB * HWSZ;       // 2*B*HW
    float* segs = gw2 + (size_t)2 * BB * HWSZ;      // B * SEGPAD
    float* tail = segs + (size_t)BB * SEGPAD + 256; // pad away from segs
    u64* pflag = (u64*)tail;                        // 256 u64 (8B-aligned)
    u32* segflag = (u32*)(pflag + 256);             // 8
    // total ~19 MB << ws_size

    conv_fused<<<BB * CBANDS, 384, 0, stream>>>(pred, fltr,
                                                (float2*)g2, (float2*)gw2);
    snake_render<<<BB * NCHUNK, 384, 0, stream>>>(pred, nodes, widths, g2, gw2,
                                                  segs, pflag, segflag, out);
}

// Round 12
// 118.128 us; speedup vs baseline: 1.3163x; 1.3163x over previous
//
#include <hip/hip_runtime.h>
#include <math.h>

#define BB   8
#define HH   384
#define WW   384
#define NN   96
#define HWSZ (HH * WW)
#define NSEG (NN - 1)
#define SEGF 12
#define SEGPAD 1152                  // NSEG*SEGF = 1140, padded
#define DMAXV 15.0f
#define ROWS_PER_BLK 12
#define NCHUNK (HH / ROWS_PER_BLK)   // 32
#define CROWS 12
#define CBANDS (HH / CROWS)          // 32
#define MAGICU 0x9E3779B9u
#define XTAG   0xA5A50000u
// HW_REG_XCC_ID (id=20, offset=0, size=32) -> imm = ((32-1)<<11) | 20
#define XCCID_IMM 63508

typedef unsigned long long u64;
typedef unsigned int u32;

// Relaxed agent-scope atomic store of a float pair (8B). Tiny segs handoff only.
__device__ inline void st_pair(float* p, float lo, float hi)
{
    u64 v = ((u64)__float_as_uint(hi) << 32) | (u64)__float_as_uint(lo);
    __hip_atomic_store((u64*)p, v, __ATOMIC_RELAXED, __HIP_MEMORY_SCOPE_AGENT);
}

__device__ inline float ld_f32_coh(const float* p)
{
    u32 v = __hip_atomic_load((u32*)p, __ATOMIC_RELAXED, __HIP_MEMORY_SCOPE_AGENT);
    return __uint_as_float(v);
}

#define WAIT_ALL() asm volatile("s_waitcnt vmcnt(0) lgkmcnt(0)" ::: "memory")

// raw barrier with LDS-only drain: global loads stay in flight across it
__device__ inline void lds_barrier()
{
    asm volatile("s_waitcnt lgkmcnt(0)" ::: "memory");
    __builtin_amdgcn_sched_barrier(0);
    __builtin_amdgcn_s_barrier();
    __builtin_amdgcn_sched_barrier(0);
}

// ---------------------------------------------------------------------------
// Separable 7x7 tap recovery (exact).
// ---------------------------------------------------------------------------
__device__ inline void load_taps(const float* __restrict__ fltr,
                                 float* __restrict__ sg, float* __restrict__ sdg)
{
    int tid = threadIdx.x;
    if (tid < 7) {
        float s = 0.f;
#pragma unroll
        for (int i = 0; i < 7; ++i) s += fabsf(fltr[i * 7 + tid]);
        sg[tid] = s;
    } else if (tid < 14) {
        int r = tid - 7;
        float s = 0.f;
#pragma unroll
        for (int j = 0; j < 7; ++j) s += fltr[r * 7 + j];
        sdg[r] = s;
    }
    __syncthreads();
}

// ---------------------------------------------------------------------------
// Kernel 1: fused separable conv (normal write-back stores; dispatch boundary
// provides coherence to kernel 2).
// ---------------------------------------------------------------------------
__global__ __launch_bounds__(384) void conv_fused(
    const float* __restrict__ pred, const float* __restrict__ fltr,
    float2* __restrict__ g2, float2* __restrict__ gw2)
{
    __shared__ float sg[7], sdg[7];
    load_taps(fltr, sg, sdg);

    int blk = blockIdx.x;            // 256 blocks
    int b = blk & 7;                 // XCD co-location swizzle (perf only)
    int band = blk >> 3;
    int y0 = band * CROWS;
    int x = threadIdx.x;             // column 0..383
    const float* pb = pred + (size_t)b * HWSZ;
    bool xin = (x >= 3) && (x < WW - 3);

    float hg[7], hd[7], hga[7], hda[7];

#pragma unroll
    for (int q = 0; q < CROWS + 6; ++q) {
        float vg = 0.f, vd = 0.f, vga = 0.f, vda = 0.f;
        int r = y0 + q - 3;
        if (r >= 0 && r < HH) {
            const float* row = pb + r * WW;
            if (xin) {
#pragma unroll
                for (int k = 0; k < 7; ++k) {
                    float v  = row[x + k - 3];
                    float av = fabsf(v);
                    vg  = fmaf(v,  sg[k],  vg);
                    vd  = fmaf(v,  sdg[k], vd);
                    vga = fmaf(av, sg[k],  vga);
                    vda = fmaf(av, sdg[k], vda);
                }
            } else {
#pragma unroll
                for (int k = 0; k < 7; ++k) {
                    int ix = x + k - 3;
                    float v  = (ix >= 0 && ix < WW) ? row[ix] : 0.f;
                    float av = fabsf(v);
                    vg  = fmaf(v,  sg[k],  vg);
                    vd  = fmaf(v,  sdg[k], vd);
                    vga = fmaf(av, sg[k],  vga);
                    vda = fmaf(av, sdg[k], vda);
                }
            }
        }
        hg[q % 7] = vg; hd[q % 7] = vd; hga[q % 7] = vga; hda[q % 7] = vda;

        if (q >= 6) {
            int y = y0 + q - 6;
            float o0 = 0.f, o1 = 0.f, o2 = 0.f, o3 = 0.f;
#pragma unroll
            for (int j = 0; j < 7; ++j) {
                int s = (q - 6 + j) % 7;
                o0 = fmaf(hg[s],  sdg[j], o0);
                o1 = fmaf(hd[s],  sg[j],  o1);
                o2 = fmaf(hga[s], sdg[j], o2);
                o3 = fmaf(hda[s], sg[j],  o3);
            }
            size_t gi = (size_t)b * HWSZ + (size_t)y * WW + x;
            g2[gi]  = make_float2(o0 * 10.f, o1 * 10.f);
            gw2[gi] = make_float2(o2 * 10.f, o3 * 10.f);
        }
    }
}

// ---------------------------------------------------------------------------
// Bilinear sample on channel-interleaved 2-ch image (ref-identical math).
// ---------------------------------------------------------------------------
__device__ inline float2 bilin2i(const float2* __restrict__ img, float py, float px)
{
    float y = fminf(fmaxf(py, 0.0f), (float)(HH - 1));
    float x = fminf(fmaxf(px, 0.0f), (float)(WW - 1));
    int y0 = (int)floorf(y);
    int x0 = (int)floorf(x);
    int y1 = min(y0 + 1, HH - 1);
    bool xedge = (x0 + 1 > WW - 1);
    float wy = y - (float)y0;
    float wx = x - (float)x0;
    float4 r0 = *(const float4*)(img + y0 * WW + x0);
    float4 r1 = *(const float4*)(img + y1 * WW + x0);
    float2 v00 = make_float2(r0.x, r0.y);
    float2 v01 = xedge ? v00 : make_float2(r0.z, r0.w);
    float2 v10 = make_float2(r1.x, r1.y);
    float2 v11 = xedge ? v10 : make_float2(r1.z, r1.w);
    float w00 = (1.f - wy) * (1.f - wx);
    float w01 = (1.f - wy) * wx;
    float w10 = wy * (1.f - wx);
    float w11 = wy * wx;
    return make_float2(v00.x * w00 + v01.x * w01 + v10.x * w10 + v11.x * w11,
                       v00.y * w00 + v01.y * w01 + v10.y * w10 + v11.y * w11);
}

// write-through (coherent) seg record: 6 u64 relaxed atomic stores
__device__ inline void write_seg_wt(float* __restrict__ r,
                                    float py, float px, float qy, float qx, float wseg)
{
    float aby = qy - py, abx = qx - px;
    float denom = aby * aby + abx * abx + 1e-8f;
    float aab = py * aby + px * abx;
    float aa  = py * py + px * px;
    float reach = DMAXV + wseg;
    st_pair(r + 0,  py,  px);
    st_pair(r + 2,  aby, abx);
    st_pair(r + 4,  aab, denom);
    st_pair(r + 6,  1.0f / denom, aa);
    st_pair(r + 8,  wseg, fminf(py, qy) - reach);
    st_pair(r + 10, fmaxf(py, qy) + reach, 0.f);
}

// ---------------------------------------------------------------------------
// Kernel 2: MERGED snake + render (round-6 verified structure) + BAND-LIMITED
// XCC-VERIFIED L2 WARM in the spin blocks:
//  - snake blocks 0..7 (unchanged from round 6) publish their HW XCC_ID.
//  - spin blocks verify their own XCC_ID matches their image's snake, compute
//    the contour band (+-32px around x(y) from the INPUT nodes), and pull
//    only that band of g2+gw2 (~390 KB/image << 4MiB L2; 31-block aggregate
//    bandwidth; off the snake's critical path). Then wait on segflag.
// Warm is read-only + one tagged side word: absmax stays 0.0.
// ---------------------------------------------------------------------------
__global__ __launch_bounds__(384) void snake_render(
    const float* __restrict__ pred, const float* __restrict__ nodes,
    const float* __restrict__ widths,
    const float* __restrict__ g2f, const float* __restrict__ gw2f,
    float* __restrict__ segs, u64* __restrict__ pflag,
    u32* __restrict__ segflag, u32* __restrict__ xcdmap,
    float* __restrict__ out)
{
    __shared__ float ss[NSEG * SEGF];
    __shared__ float2 posb[2][NN];
    __shared__ float  wbuf[NN];
    __shared__ short  cxw[HH];       // spin-block warm band starts
    __shared__ u32    sxm;
    __shared__ int slo, shi;
    __shared__ float swsum[6];

    int blk = blockIdx.x;            // 256 blocks
    int b   = blk & 7;               // image (XCD co-location, perf-only)
    int band = blk >> 3;             // render chunk
    int t = threadIdx.x;

    int y0r = band * ROWS_PER_BLK;
    const float* pb = pred + (size_t)b * HWSZ + (size_t)y0r * WW + t;
    float pv[ROWS_PER_BLK];
#pragma unroll
    for (int ry = 0; ry < ROWS_PER_BLK; ++ry) pv[ry] = pb[ry * WW];

    if (t == 0) { slo = NSEG; shi = -1; }

    // ================= phase B: snake (blocks 0..7) =================
    if (blk < 8) {
        if (t == 0) {
            u32 xid = __builtin_amdgcn_s_getreg(XCCID_IMM) & 0xFu;
            __hip_atomic_store(&xcdmap[b], XTAG | xid,
                               __ATOMIC_RELAXED, __HIP_MEMORY_SCOPE_AGENT);
        }

        const float2* gb  = (const float2*)g2f  + (size_t)b * HWSZ;
        const float2* gwb = (const float2*)gw2f + (size_t)b * HWSZ;
        int wv = t >> 6, ln = t & 63;
        int n  = wv * 48 + ln;            // node index (balanced 48/48)
        bool act = (wv < 2) && (ln < 48);
        bool n0f = (n == 0), nlf = (n == NN - 1);

        float py = 0.f, px = 0.f;
        float4 r0 = make_float4(0.f, 0.f, 0.f, 0.f), r1 = r0;
        float wy = 0.f, wx = 0.f;
        bool xedge = false;

        // prologue: load node, publish to LDS, issue gather for initial pos
        if (act) {
            float2 p0 = *(const float2*)(nodes + (size_t)(b * NN + n) * 2);
            py = p0.x; px = p0.y;
            posb[0][n] = p0;
            float yc = fminf(fmaxf(py, 0.0f), (float)(HH - 1));
            float xc = fminf(fmaxf(px, 0.0f), (float)(WW - 1));
            int y0i = (int)floorf(yc);
            int x0i = (int)floorf(xc);
            int y1i = min(y0i + 1, HH - 1);
            xedge = (x0i + 1 > WW - 1);
            wy = yc - (float)y0i;
            wx = xc - (float)x0i;
            r0 = *(const float4*)(gb + y0i * WW + x0i);
            r1 = *(const float4*)(gb + y1i * WW + x0i);
        }
        lds_barrier();                    // all 6 waves of the block

        // ---- 50 position steps, software-pipelined ----
        for (int s = 0; s < 50; ++s) {
            const float2* pcur = posb[s & 1];
            float2* pnxt = posb[(s & 1) ^ 1];
            if (act) {
                // LDS exchange + internal forces (overlaps in-flight gathers)
                float2 xm1 = pcur[max(n - 1, 0)];
                float2 xp1 = pcur[min(n + 1, NN - 1)];
                float2 xm2 = pcur[max(n - 2, 0)];
                float2 xp2 = pcur[min(n + 2, NN - 1)];

                float d2m_y = xm2.x - 2.f * xm1.x + py;
                float d2c_y = xm1.x - 2.f * py + xp1.x;
                float d2p_y = py - 2.f * xp1.x + xp2.x;
                float d2m_x = xm2.y - 2.f * xm1.y + px;
                float d2c_x = xm1.y - 2.f * px + xp1.y;
                float d2p_x = px - 2.f * xp1.y + xp2.y;
                d2m_y = n0f ? d2c_y : d2m_y;
                d2m_x = n0f ? d2c_x : d2m_x;
                d2p_y = nlf ? d2c_y : d2p_y;
                d2p_x = nlf ? d2c_x : d2p_x;
                float d4_y = d2m_y - 2.f * d2c_y + d2p_y;
                float d4_x = d2m_x - 2.f * d2c_x + d2p_x;

                // consume the gather issued LAST iteration (weights carried)
                float2 v00 = make_float2(r0.x, r0.y);
                float2 v01 = xedge ? v00 : make_float2(r0.z, r0.w);
                float2 v10 = make_float2(r1.x, r1.y);
                float2 v11 = xedge ? v10 : make_float2(r1.z, r1.w);
                float w00 = (1.f - wy) * (1.f - wx);
                float w01 = (1.f - wy) * wx;
                float w10 = wy * (1.f - wx);
                float w11 = wy * wx;
                float fy = v00.x * w00 + v01.x * w01 + v10.x * w10 + v11.x * w11;
                float fx = v00.y * w00 + v01.y * w01 + v10.y * w10 + v11.y * w11;

                py += 0.1f * (0.01f * d2c_y - 0.01f * d4_y + fy);
                px += 0.1f * (0.01f * d2c_x - 0.01f * d4_x + fx);

                // issue NEXT step's gather from the updated position
                float yc = fminf(fmaxf(py, 0.0f), (float)(HH - 1));
                float xc = fminf(fmaxf(px, 0.0f), (float)(WW - 1));
                int y0i = (int)floorf(yc);
                int x0i = (int)floorf(xc);
                int y1i = min(y0i + 1, HH - 1);
                xedge = (x0i + 1 > WW - 1);
                wy = yc - (float)y0i;
                wx = xc - (float)x0i;
                r0 = *(const float4*)(gb + y0i * WW + x0i);
                r1 = *(const float4*)(gb + y1i * WW + x0i);

                pnxt[n] = make_float2(py, px);
            }
            lds_barrier();             // LDS drain only; gathers stay in flight
        }
        // final positions: posb[0][*] and (py,px) registers

        // ---- tangent / normal / width loop ----
        float ny_ = 0.f, nx_ = 0.f, wn = 0.f;
        if (act) {
            float2 xm1 = posb[0][max(n - 1, 0)];
            float2 xp1 = posb[0][min(n + 1, NN - 1)];
            float ty, tx;
            if (n0f)      { ty = xp1.x - py;  tx = xp1.y - px; }
            else if (nlf) { ty = py - xm1.x;  tx = px - xm1.y; }
            else          { ty = 0.5f * (xp1.x - xm1.x); tx = 0.5f * (xp1.y - xm1.y); }

            float nn0 = -tx, nn1 = ty;
            float nrm = sqrtf(nn0 * nn0 + nn1 * nn1) + 1e-6f;
            ny_ = nn0 / nrm; nx_ = nn1 / nrm;

            wn = widths[b * NN + n];
            for (int s = 0; s < 10; ++s) {
                float2 gp = bilin2i(gwb, py + wn * ny_, px + wn * nx_);
                float2 gm = bilin2i(gwb, py - wn * ny_, px - wn * nx_);
                float fw = 0.5f * ((gp.x * ny_ + gp.y * nx_) - (gm.x * ny_ + gm.y * nx_));
                wn = fmaxf(wn + 0.1f * fw, 0.5f);
            }
            wbuf[n] = wn;
        }
        __syncthreads();               // wbuf ready

        // ---- seg write: tiny write-through handoff ----
        if (act && n < NSEG) {
            float2 q = posb[0][n + 1];
            float wq = wbuf[n + 1];
            write_seg_wt(segs + (size_t)b * SEGPAD + (size_t)n * SEGF,
                         py, px, q.x, q.y, 0.5f * (wn + wq));
        }
        WAIT_ALL();                    // this wave's seg stores committed
        __syncthreads();               // all waves committed
        if (t == 0)
            __hip_atomic_store(&segflag[b], MAGICU,
                               __ATOMIC_RELAXED, __HIP_MEMORY_SCOPE_AGENT);
    } else {
        // ---- band-limited, XCC-verified L2 warm, then wait ----
        if (t == 0) {
            u32 m;
            while (((m = __hip_atomic_load(&xcdmap[b], __ATOMIC_RELAXED,
                                           __HIP_MEMORY_SCOPE_AGENT))
                    & 0xFFFF0000u) != XTAG)
                __builtin_amdgcn_s_sleep(1);
            sxm = m;
        }
        __syncthreads();
        u32 myx = __builtin_amdgcn_s_getreg(XCCID_IMM) & 0xFu;
        if ((sxm & 0xFu) == myx) {
            // stage this image's nodes (768 B) into posb[0] (unused here)
            for (int i = t; i < NN; i += 384)
                posb[0][i] = *(const float2*)(nodes + (size_t)(b * NN + i) * 2);
            __syncthreads();
            // per-row band start from the initial contour (perf-only)
            for (int r = t; r < HH; r += 384) {
                float yy = (float)r;
                float2 p0 = posb[0][0], pl = posb[0][NN - 1];
                float xi;
                if (yy <= p0.x) xi = p0.y;
                else if (yy >= pl.x) xi = pl.y;
                else {
                    int i = 0;
                    for (int k = 0; k < NN - 1; ++k)
                        if (posb[0][k].x <= yy) i = k;
                    float2 a = posb[0][i], c = posb[0][i + 1];
                    xi = a.y + (c.y - a.y) * ((yy - a.x) / fmaxf(c.x - a.x, 1e-6f));
                }
                int cx = ((int)xi - 32);
                cxw[r] = (short)(max(0, min(cx, WW - 64)) & ~1);
            }
            __syncthreads();
            // pull the +-32px band of g2 AND gw2 (rank-partitioned rows)
            const float2* gbp  = (const float2*)g2f  + (size_t)b * HWSZ;
            const float2* gwbp = (const float2*)gw2f + (size_t)b * HWSZ;
            int rank = band - 1;                  // 0..30
            float acc = 0.f;
            if (t < 64) {
                int pl2 = t >> 5, c = t & 31;     // plane, float4 index
                for (int r = rank; r < HH; r += 31) {
                    int c0 = (int)cxw[r];
                    const float4* w = pl2
                        ? (const float4*)(gwbp + (size_t)r * WW + c0)
                        : (const float4*)(gbp  + (size_t)r * WW + c0);
                    float4 a = w[c];
                    acc += a.x;
                }
            }
            asm volatile("" :: "v"(acc));          // DCE guard (rule #17)
        }
        if (t == 0) {
            while (__hip_atomic_load(&segflag[b],
                                     __ATOMIC_RELAXED, __HIP_MEMORY_SCOPE_AGENT) != MAGICU)
                __builtin_amdgcn_s_sleep(8);
            asm volatile("" ::: "memory");
        }
    }

    __syncthreads();                 // segs ready; slo/shi initialized

    // ================= phase C: render 12 rows + partial sum =================
    {
        int y0 = y0r;
        const float* sb = segs + (size_t)b * SEGPAD;
        for (int j = t; j < NSEG * SEGF; j += 384)
            ss[j] = ld_f32_coh(sb + j);      // one-shot coherent staging
        __syncthreads();

        float cy0 = (float)y0, cy1 = (float)(y0 + ROWS_PER_BLK - 1);
        if (t < NSEG) {
            float ylo = ss[t * SEGF + 9];
            float yhi = ss[t * SEGF + 10];
            if (yhi >= cy0 && ylo <= cy1) {
                atomicMin(&slo, t);
                atomicMax(&shi, t);
            }
        }
        __syncthreads();
        int lo = slo, hi = shi;

        float px = (float)t;
        float px2 = px * px;
        float minv[ROWS_PER_BLK];
#pragma unroll
        for (int r = 0; r < ROWS_PER_BLK; ++r) minv[r] = DMAXV;

        for (int si = lo; si <= hi; ++si) {
            const float* r = ss + si * SEGF;
            float ax = r[1], abx = r[3], ws = r[8];
            float bxe = ax + abx;
            float reach = DMAXV + ws + 0.01f;
            if (px < fminf(ax, bxe) - reach || px > fmaxf(ax, bxe) + reach) continue;

            float ay = r[0], aby = r[2];
            float aab = r[4], denom = r[5], invd = r[6], aa = r[7];
            float dotpa_b = fmaf(px, abx, -aab);
            float pa2_b   = fmaf(px, -2.0f * ax, px2 + aa);
#pragma unroll
            for (int ry = 0; ry < ROWS_PER_BLK; ++ry) {
                float py = (float)(y0 + ry);
                float dotpa = fmaf(py, aby, dotpa_b);
                float tt = fminf(fmaxf(dotpa * invd, 0.0f), 1.0f);
                float pa2 = fmaf(py, fmaf(py, 1.0f, -2.0f * ay), pa2_b);
                float d2 = fmaf(tt, fmaf(tt, denom, -2.0f * dotpa), pa2);
                float d = sqrtf(fmaxf(d2, 0.0f));
                float v = fmaxf(d - ws, 0.0f);
                minv[ry] = fminf(minv[ry], v);
            }
        }

        float sq = 0.f;
#pragma unroll
        for (int ry = 0; ry < ROWS_PER_BLK; ++ry) {
            float diff = pv[ry] - minv[ry];
            sq = fmaf(diff, diff, sq);
        }

#pragma unroll
        for (int off = 32; off > 0; off >>= 1) sq += __shfl_down(sq, off, 64);
        if ((t & 63) == 0) swsum[t >> 6] = sq;
        __syncthreads();
        if (t == 0) {
            float tot = swsum[0] + swsum[1] + swsum[2] + swsum[3] + swsum[4] + swsum[5];
            u64 pvv = ((u64)MAGICU << 32) | (u64)__float_as_uint(tot);
            __hip_atomic_store(&pflag[blk], pvv,
                               __ATOMIC_RELAXED, __HIP_MEMORY_SCOPE_AGENT);
        }
    }

    // ================= final reduce: designated block 8 =================
    if (blk == 8) {
        __syncthreads();             // protect swsum reuse
        float v = 0.f;
        if (t < 256) {
            u64 pvv = __hip_atomic_load(&pflag[t], __ATOMIC_RELAXED,
                                        __HIP_MEMORY_SCOPE_AGENT);
            while ((u32)(pvv >> 32) != MAGICU) {
                __builtin_amdgcn_s_sleep(4);
                pvv = __hip_atomic_load(&pflag[t], __ATOMIC_RELAXED,
                                        __HIP_MEMORY_SCOPE_AGENT);
            }
            v = __uint_as_float((u32)pvv);
        }
#pragma unroll
        for (int off = 32; off > 0; off >>= 1) v += __shfl_down(v, off, 64);
        if ((t & 63) == 0) swsum[t >> 6] = v;
        __syncthreads();
        if (t == 0) {
            float tot = swsum[0] + swsum[1] + swsum[2] + swsum[3] + swsum[4] + swsum[5];
            out[0] = tot * (1.0f / (float)(BB * HWSZ));
        }
    }
}

extern "C" void kernel_launch(void* const* d_in, const int* in_sizes, int n_in,
                              void* d_out, int out_size, void* d_ws, size_t ws_size,
                              hipStream_t stream)
{
    const float* pred   = (const float*)d_in[0];   // (8,1,384,384)
    const float* nodes  = (const float*)d_in[1];   // (8,96,2)
    const float* widths = (const float*)d_in[2];   // (8,96)
    const float* fltr   = (const float*)d_in[3];   // (2,1,7,7)
    float* out = (float*)d_out;

    float* ws   = (float*)d_ws;
    float* g2   = ws;                               // 2*B*HW floats (float2 lanes)
    float* gw2  = g2 + (size_t)2 * BB * HWSZ;       // 2*B*HW
    float* segs = gw2 + (size_t)2 * BB * HWSZ;      // B * SEGPAD
    float* tail = segs + (size_t)BB * SEGPAD + 256; // pad away from segs
    u64* pflag = (u64*)tail;                        // 256 u64 (8B-aligned)
    u32* segflag = (u32*)(pflag + 256);             // 8
    u32* xcdmap  = segflag + 8;                     // 8
    // total ~19 MB << ws_size

    conv_fused<<<BB * CBANDS, 384, 0, stream>>>(pred, fltr,
                                                (float2*)g2, (float2*)gw2);
    snake_render<<<BB * NCHUNK, 384, 0, stream>>>(pred, nodes, widths, g2, gw2,
                                                  segs, pflag, segflag, xcdmap,
                                                  out);
}